// Round 6
// baseline (1999.944 us; speedup 1.0000x reference)
//
#include <hip/hip_runtime.h>
#include <stdint.h>

#define ALPHA 0.1f
#define NN 20000
#define DF 768
#define NE 200000
#define NB 64
#define TSEQ 128
#define SF 128
#define HS 512
#define NCLS 14

typedef __attribute__((ext_vector_type(8))) short short8;
typedef __attribute__((ext_vector_type(4))) float f32x4;

// ---------------- workspace layout (bytes) ----------------
// NOTE (R6 fix): hbuf is u32[2][2][64][512] = 524288 B. R4/R5 under-allocated
// it (262144), so slot-1 exchange traffic stomped y_seq -> absmax ~1.14.
#define OFF_DEG     0u           // int[20000]
#define OFF_CSRC    80000u       // int[20000]
#define OFF_CNTB    160000u      // int[64]
#define OFF_MHBAR   160256u      // u32[16] multihop barrier
#define ZERO_INTS   40080u       // zero [0, 160320)
#define OFF_FLAG64  160320u      // int[1] (outside zero range; written by prep)
#define OFF_ROWPTR  160384u      // int[20001]
#define OFF_CURSOR  240640u      // int[20000]
#define OFF_DINV    320640u      // float[20000]
#define OFF_COL     400640u      // int[200000]
#define OFF_WGT     1200640u     // float[200000]
#define OFF_V0      2000640u     // float[20000*64]
#define OFF_V1      7120640u     // float[20000*64]
#define OFF_HBUF    12240640u    // u32 [2][2][64][512]  (tag<<16 | bf16 h)  524288 B
#define OFF_YSEQ    12764928u    // float[64*1024]
#define OFF_PART    13027072u    // float[32][64][768]

__device__ __forceinline__ unsigned short f2b(float f) {
  union { float f; unsigned u; } v; v.f = f;
  unsigned u = v.u;
  return (unsigned short)((u + 0x7FFFu + ((u >> 16) & 1u)) >> 16);
}

__device__ __forceinline__ int idx_at(const int* p, long long i, int mode64) {
  return mode64 ? p[2*i] : p[i];   // little-endian low word
}

// ---------------- prep: zero counters + parallel i64 detect ----------------
__global__ void prep_kernel(int* p, const int* e, int* flag) {
  int tid = threadIdx.x;
  if (blockIdx.x == gridDim.x - 1) {
    if (tid < 64) {
      int nz = 0;
#pragma unroll
      for (int j = 0; j < 4; ++j) nz |= e[2 * (tid * 4 + j) + 1];
      unsigned long long m = __ballot(nz != 0);
      if (tid == 0) *flag = (m == 0ull) ? 1 : 0;
    }
    return;
  }
  int i = blockIdx.x * 256 + tid;
  if (i < (int)ZERO_INTS) p[i] = 0;
}

__global__ void hist_kernel(const int* e, const int* batch, int* deg, int* csrc,
                            int* cntb, const int* flag) {
  int i = blockIdx.x * blockDim.x + threadIdx.x;
  int m = *flag;
  if (i < NE) {
    int s = idx_at(e, i, m);
    int d = idx_at(e, (long long)NE + i, m);
    atomicAdd(&csrc[s], 1);
    atomicAdd(&deg[d], 1);
  }
  if (i < NN) atomicAdd(&cntb[idx_at(batch, i, m)], 1);
}

__global__ void dinv_kernel(const int* deg, float* dinv) {
  int i = blockIdx.x * blockDim.x + threadIdx.x;
  if (i < NN) dinv[i] = rsqrtf((float)(deg[i] + 1));   // +1 self loop, >=1
}

// single-block scan, wave-shuffle based
__global__ void scan_kernel(const int* cnt, int* row_ptr, int* cursor) {
  __shared__ int wsum[16];
  int tid = threadIdx.x, lane = tid & 63, w = tid >> 6;
  int carry = 0;
  const int nch = (NN + 1023) / 1024;
  for (int c = 0; c < nch; ++c) {
    int i = c * 1024 + tid;
    int v = (i < NN) ? cnt[i] : 0;
    int s = v;
#pragma unroll
    for (int off = 1; off < 64; off <<= 1) {
      int o = __shfl_up(s, off);
      if (lane >= off) s += o;
    }
    if (lane == 63) wsum[w] = s;
    __syncthreads();
    if (w == 0 && lane < 16) {
      int ws_ = wsum[lane];
#pragma unroll
      for (int off = 1; off < 16; off <<= 1) {
        int o = __shfl_up(ws_, off);
        if (lane >= off) ws_ += o;
      }
      wsum[lane] = ws_;
    }
    __syncthreads();
    int ex = carry + (w ? wsum[w - 1] : 0) + s - v;
    if (i < NN) { row_ptr[i] = ex; cursor[i] = ex; }
    carry += wsum[15];
    __syncthreads();
  }
  if (tid == 0) row_ptr[NN] = carry;
}

__global__ void fill_kernel(const int* e, const float* dinv, int* cursor,
                            int* colA, float* wgt, const int* flag) {
  int i = blockIdx.x * blockDim.x + threadIdx.x;
  if (i >= NE) return;
  int m = *flag;
  int s = idx_at(e, i, m);
  int d = idx_at(e, (long long)NE + i, m);
  int pos = atomicAdd(&cursor[s], 1);
  colA[pos] = d;
  wgt[pos] = dinv[s] * dinv[d];
}

__global__ void v0init_kernel(const int* batch, float* v0, const int* flag) {
  int i = blockIdx.x * blockDim.x + threadIdx.x;
  if (i >= NN * 64) return;
  int n = i >> 6, b = i & 63;
  v0[i] = (idx_at(batch, n, *flag) == b) ? 1.0f : 0.0f;
}

// ---------------- fused 16-hop APPNP (persistent, device barrier) ----------
__global__ __launch_bounds__(1024, 4) void multihop_kernel(
    float* __restrict__ V0, float* __restrict__ V1,
    const int* __restrict__ row_ptr, const int* __restrict__ colA,
    const float* __restrict__ wgt, const float* __restrict__ dinv,
    const int* __restrict__ batch, const int* __restrict__ flag,
    unsigned* __restrict__ bar) {
  const int tid = threadIdx.x;
  const int lane = tid & 63;
  const int gwave = (blockIdx.x * 1024 + tid) >> 6;  // 0..4095
  const int m64 = *flag;
  for (int h = 0; h < 16; ++h) {
    const float* vin = (h & 1) ? V1 : V0;
    float* vout = (h & 1) ? V0 : V1;
    for (int n = gwave; n < NN; n += 4096) {
      float di = dinv[n];
      float acc = di * di * __hip_atomic_load(&vin[(size_t)n * 64 + lane],
                                              __ATOMIC_RELAXED, __HIP_MEMORY_SCOPE_AGENT);
      int e0 = row_ptr[n], e1 = row_ptr[n + 1];
      int e = e0;
      for (; e + 4 <= e1; e += 4) {
        int c0 = colA[e], c1 = colA[e + 1], c2 = colA[e + 2], c3 = colA[e + 3];
        float w0 = wgt[e], w1 = wgt[e + 1], w2 = wgt[e + 2], w3 = wgt[e + 3];
        float v0 = __hip_atomic_load(&vin[(size_t)c0 * 64 + lane], __ATOMIC_RELAXED, __HIP_MEMORY_SCOPE_AGENT);
        float v1 = __hip_atomic_load(&vin[(size_t)c1 * 64 + lane], __ATOMIC_RELAXED, __HIP_MEMORY_SCOPE_AGENT);
        float v2 = __hip_atomic_load(&vin[(size_t)c2 * 64 + lane], __ATOMIC_RELAXED, __HIP_MEMORY_SCOPE_AGENT);
        float v3 = __hip_atomic_load(&vin[(size_t)c3 * 64 + lane], __ATOMIC_RELAXED, __HIP_MEMORY_SCOPE_AGENT);
        acc += w0 * v0 + w1 * v1 + w2 * v2 + w3 * v3;
      }
      for (; e < e1; ++e)
        acc += wgt[e] * __hip_atomic_load(&vin[(size_t)colA[e] * 64 + lane],
                                          __ATOMIC_RELAXED, __HIP_MEMORY_SCOPE_AGENT);
      float y0 = (idx_at(batch, n, m64) == lane) ? ALPHA : 0.0f;
      __hip_atomic_store(&vout[(size_t)n * 64 + lane], (1.0f - ALPHA) * acc + y0,
                         __ATOMIC_RELAXED, __HIP_MEMORY_SCOPE_AGENT);
    }
    if (h < 15) {   // device barrier (syncthreads drains this block's stores)
      __syncthreads();
      if (tid == 0) {
        __hip_atomic_fetch_add(bar, 1u, __ATOMIC_ACQ_REL, __HIP_MEMORY_SCOPE_AGENT);
        unsigned target = 256u * (unsigned)(h + 1);
        int guard = 0;
        while (__hip_atomic_load(bar, __ATOMIC_ACQUIRE, __HIP_MEMORY_SCOPE_AGENT) < target) {
          __builtin_amdgcn_s_sleep(2);
          if (++guard > (1 << 22)) break;   // wrong answer beats a hang
        }
      }
      __syncthreads();
    }
  }
}

// pooled_unnorm partials: 48 f-tiles x 32 node-chunks, lane = graph id
__global__ void spmm_kernel(const float* __restrict__ S, const float* __restrict__ x,
                            float* __restrict__ partial) {
  int wid = (blockIdx.x * blockDim.x + threadIdx.x) >> 6;   // 1536 waves
  int lane = threadIdx.x & 63;
  int ft = wid % 48, ch = wid / 48;
  if (ch >= 32) return;
  int f0 = ft * 16;
  int n0 = ch * 625, n1 = n0 + 625;
  float acc[16];
#pragma unroll
  for (int f = 0; f < 16; ++f) acc[f] = 0.0f;
  for (int n = n0; n < n1; ++n) {
    float sv = S[n * 64 + lane];
    const float* xr = x + (size_t)n * DF + f0;
#pragma unroll
    for (int f = 0; f < 16; ++f) acc[f] += sv * xr[f];
  }
  float* pr = partial + ((size_t)(ch * 64 + lane)) * DF + f0;
#pragma unroll
  for (int f = 0; f < 16; ++f) pr[f] = acc[f];
}

// ---------------- fused readout heads: both MLPs + pooled reduce ------------
__global__ __launch_bounds__(256) void heads_kernel(
    const float* __restrict__ y_seq, const float* __restrict__ part,
    const int* __restrict__ cntb,
    const float* __restrict__ ms_w0, const float* __restrict__ ms_b0,
    const float* __restrict__ ms_w1, const float* __restrict__ ms_b1,
    const float* __restrict__ ms_w2, const float* __restrict__ ms_b2,
    const float* __restrict__ mg_w0, const float* __restrict__ mg_b0,
    const float* __restrict__ mg_w1, const float* __restrict__ mg_b1,
    const float* __restrict__ mg_w2, const float* __restrict__ mg_b2,
    float* __restrict__ out) {
  __shared__ float buf[1024], h1[512], h2[256], lg[16];
  const int b = blockIdx.x, tid = threadIdx.x;
  // ---- seq MLP: 1024 -> 512 -> 256 -> 14 ----
  for (int i = tid; i < 1024; i += 256) buf[i] = y_seq[(size_t)b * 1024 + i];
  __syncthreads();
  for (int n = tid; n < 512; n += 256) {
    float a = ms_b0[n];
    const float* w = ms_w0 + (size_t)n * 1024;
    for (int k = 0; k < 1024; k += 4)
      a += buf[k] * w[k] + buf[k+1] * w[k+1] + buf[k+2] * w[k+2] + buf[k+3] * w[k+3];
    h1[n] = fmaxf(a, 0.0f);
  }
  __syncthreads();
  for (int n = tid; n < 256; n += 256) {
    float a = ms_b1[n];
    const float* w = ms_w1 + (size_t)n * 512;
    for (int k = 0; k < 512; k += 4)
      a += h1[k] * w[k] + h1[k+1] * w[k+1] + h1[k+2] * w[k+2] + h1[k+3] * w[k+3];
    h2[n] = fmaxf(a, 0.0f);
  }
  __syncthreads();
  if (tid < NCLS) {
    float a = ms_b2[tid];
    const float* w = ms_w2 + (size_t)tid * 256;
    for (int k = 0; k < 256; k += 4)
      a += h2[k] * w[k] + h2[k+1] * w[k+1] + h2[k+2] * w[k+2] + h2[k+3] * w[k+3];
    lg[tid] = a;
  }
  __syncthreads();
  // ---- pooled = sum(part chunks)/cnt ----
  float cinv = 1.0f / fmaxf((float)cntb[b], 1.0f);
  for (int i = tid; i < 768; i += 256) {
    float s = 0.0f;
    for (int c = 0; c < 32; ++c) s += part[((size_t)(c * 64 + b)) * 768 + i];
    buf[i] = s * cinv;
  }
  __syncthreads();
  // ---- graph MLP: 768 -> 384 -> 192 -> 14 ----
  for (int n = tid; n < 384; n += 256) {
    float a = mg_b0[n];
    const float* w = mg_w0 + (size_t)n * 768;
    for (int k = 0; k < 768; k += 4)
      a += buf[k] * w[k] + buf[k+1] * w[k+1] + buf[k+2] * w[k+2] + buf[k+3] * w[k+3];
    h1[n] = fmaxf(a, 0.0f);
  }
  __syncthreads();
  for (int n = tid; n < 192; n += 256) {
    float a = mg_b1[n];
    const float* w = mg_w1 + (size_t)n * 384;
    for (int k = 0; k < 384; k += 4)
      a += h1[k] * w[k] + h1[k+1] * w[k+1] + h1[k+2] * w[k+2] + h1[k+3] * w[k+3];
    h2[n] = fmaxf(a, 0.0f);
  }
  __syncthreads();
  if (tid < NCLS) {
    float a = mg_b2[tid];
    const float* w = mg_w2 + (size_t)tid * 192;
    for (int k = 0; k < 192; k += 4)
      a += h2[k] * w[k] + h2[k+1] * w[k+1] + h2[k+2] * w[k+2] + h2[k+3] * w[k+3];
    out[b * NCLS + tid] = lg[tid] + a;
  }
}

// ---------------- GRU recurrent kernel (R3-proven: staggered, u32 tagged) ---
// 256 blocks = 8 groups (8 seqs each) x 32 ranks (16 h-cols per dir each).
#define GRU_LDS_BYTES 155648

__global__ __launch_bounds__(384, 1) void gru_kernel(
    const float* __restrict__ seq,
    const float* __restrict__ wih_f, const float* __restrict__ whh_f,
    const float* __restrict__ bih_f, const float* __restrict__ bhh_f,
    const float* __restrict__ wih_b, const float* __restrict__ whh_b,
    const float* __restrict__ bih_b, const float* __restrict__ bhh_b,
    unsigned* __restrict__ hbuf, float* __restrict__ y_seq) {
  extern __shared__ char smem_raw[];
  unsigned short* W1 = (unsigned short*)smem_raw;     // [2][48][648]
  unsigned short* hl = W1 + 2 * 48 * 648;             // [2][8][648]
  float* ghs = (float*)(hl + 2 * 8 * 648);            // [2][64][8]

  const int tid = threadIdx.x;
  const int wave = tid >> 6, lane = tid & 63;
  const int quad = lane >> 4, l15 = lane & 15;
  const int g = blockIdx.x >> 5;          // 8 groups
  const int rk = blockIdx.x & 31;         // 32 ranks
  const int seqbase = g * 8;
  const int c0 = rk * 16;

  const float* WHH[2] = {whh_f, whh_b};
  const float* WIH[2] = {wih_f, wih_b};
  const float* BIH[2] = {bih_f, bih_b};
  const float* BHH[2] = {bhh_f, bhh_b};

  // ---- stationary weights -> LDS (fp32 -> bf16) ----
  for (int i = tid; i < 2 * 48 * 640; i += 384) {
    int d = i / 30720;
    int rrow = (i - d * 30720) / 640;
    int c = i - d * 30720 - rrow * 640;
    int gcol = (rrow < 16) ? (c0 + rrow)
             : (rrow < 32) ? (512 + c0 + (rrow - 16))
                           : (1024 + c0 + (rrow - 32));
    float val = (c < 512) ? WHH[d][gcol * 512 + c] : WIH[d][gcol * 128 + (c - 512)];
    W1[(d * 48 + rrow) * 648 + c] = f2b(val);
  }
  // ---- hl init: h(0)=0; stage x(0) for both dirs ----
  for (int i = tid; i < 2 * 8 * 512; i += 384) {
    int d = i >> 12;
    int rem = i & 4095; int s = rem >> 9, c = rem & 511;
    hl[(d * 8 + s) * 648 + c] = 0;
  }
  for (int i = tid; i < 2 * 8 * 128; i += 384) {
    int d = i >> 10; int rem = i & 1023; int s = rem >> 7, k = rem & 127;
    int tt = d ? 127 : 0;
    hl[(d * 8 + s) * 648 + 512 + k] =
        f2b(seq[(size_t)(seqbase + s) * (TSEQ * SF) + tt * SF + k]);
  }

  float b_r[2] = {0, 0}, b_z[2] = {0, 0}, b_in[2] = {0, 0}, b_hn[2] = {0, 0};
  float hprev[2] = {0, 0}, msum[2] = {0, 0}, mx[2] = {-1e30f, -1e30f};
  const int seq_i = (tid >> 4) & 7, col_i = tid & 15;
  if (tid < 128) {
#pragma unroll
    for (int d = 0; d < 2; ++d) {
      b_r[d]  = BIH[d][c0 + col_i] + BHH[d][c0 + col_i];
      b_z[d]  = BIH[d][512 + c0 + col_i] + BHH[d][512 + c0 + col_i];
      b_in[d] = BIH[d][1024 + c0 + col_i];
      b_hn[d] = BHH[d][1024 + c0 + col_i];
    }
  }
  __syncthreads();

  auto do_gemm = [&](int d, int wrole) {
    f32x4 accH = {0, 0, 0, 0}, accX = {0, 0, 0, 0};
    const unsigned short* arow = hl + d * 5184 + l15 * 648 + quad * 8;
    const unsigned short* brow = W1 + d * 31104 + (wrole * 16 + l15) * 648 + quad * 8;
    if (wrole < 2) {          // r or z: fused K=640 over [h|x]
#pragma unroll
      for (int kc = 0; kc < 20; ++kc)
        accH = __builtin_amdgcn_mfma_f32_16x16x32_bf16(
            *(const short8*)(arow + kc * 32), *(const short8*)(brow + kc * 32),
            accH, 0, 0, 0);
      float* gd = ghs + d * 512 + (wrole * 16 + l15) * 8;
#pragma unroll
      for (int rr = 0; rr < 4; ++rr) { int m = quad * 4 + rr; if (m < 8) gd[m] = accH[rr]; }
    } else {                  // n: h-part (K=512) and x-part (K=128) separate
#pragma unroll
      for (int kc = 0; kc < 16; ++kc)
        accH = __builtin_amdgcn_mfma_f32_16x16x32_bf16(
            *(const short8*)(arow + kc * 32), *(const short8*)(brow + kc * 32),
            accH, 0, 0, 0);
#pragma unroll
      for (int kc = 0; kc < 4; ++kc)
        accX = __builtin_amdgcn_mfma_f32_16x16x32_bf16(
            *(const short8*)(arow + 512 + kc * 32), *(const short8*)(brow + 512 + kc * 32),
            accX, 0, 0, 0);
      float* gdh = ghs + d * 512 + (32 + l15) * 8;
      float* gdx = ghs + d * 512 + (48 + l15) * 8;
#pragma unroll
      for (int rr = 0; rr < 4; ++rr) {
        int m = quad * 4 + rr;
        if (m < 8) { gdh[m] = accH[rr]; gdx[m] = accX[rr]; }
      }
    }
  };

  // gather h(tag) for dir d into hl + stage x(t_x); run by 192 threads (l192)
  auto do_gather_stage = [&](int d, int t_x, int slot, unsigned tagexp, int l192) {
    if (t_x >= 0 && t_x < 128) {   // stage x (overlaps the tag-poll latency)
      int tt = d ? (127 - t_x) : t_x;
#pragma unroll
      for (int j = 0; j < 6; ++j) {
        int flat = l192 + 192 * j;
        if (flat < 1024) {
          int s = flat >> 7, k = flat & 127;
          hl[d * 5184 + s * 648 + 512 + k] =
              f2b(seq[(size_t)(seqbase + s) * (TSEQ * SF) + tt * SF + k]);
        }
      }
    }
    unsigned v[22];
    int guard = 0;
    for (;;) {
      int ok = 1;
#pragma unroll
      for (int j = 0; j < 22; ++j) {
        int flat = l192 + 192 * j;
        if (flat < 4096) {
          v[j] = __hip_atomic_load(
              &hbuf[((size_t)((slot * 2 + d) * 64 + seqbase + (flat >> 9))) * 512 +
                    (flat & 511)],
              __ATOMIC_RELAXED, __HIP_MEMORY_SCOPE_AGENT);
          ok &= (int)((v[j] >> 16) == tagexp);
        }
      }
      if (ok || ++guard > (1 << 18)) break;
      __builtin_amdgcn_s_sleep(1);
    }
#pragma unroll
    for (int j = 0; j < 22; ++j) {
      int flat = l192 + 192 * j;
      if (flat < 4096)
        hl[d * 5184 + (flat >> 9) * 648 + (flat & 511)] =
            (unsigned short)(v[j] & 0xFFFFu);
    }
  };

  auto do_gates = [&](int d, int t) {
    const float* gd = ghs + d * 512;
    float gr = gd[col_i * 8 + seq_i];
    float gz = gd[(16 + col_i) * 8 + seq_i];
    float gh = gd[(32 + col_i) * 8 + seq_i];
    float gx = gd[(48 + col_i) * 8 + seq_i];
    float r = 1.0f / (1.0f + __expf(-(gr + b_r[d])));
    float z = 1.0f / (1.0f + __expf(-(gz + b_z[d])));
    float narg = gx + b_in[d] + r * (gh + b_hn[d]);
    float e2 = __expf(-2.0f * fabsf(narg));
    float nt = (1.0f - e2) / (1.0f + e2);
    nt = (narg < 0.0f) ? -nt : nt;
    float h2 = (1.0f - z) * nt + z * hprev[d];
    hprev[d] = h2; msum[d] += h2; mx[d] = fmaxf(mx[d], h2);
    if (t < 127) {
      unsigned pk = ((unsigned)(t + 1) << 16) | (unsigned)f2b(h2);
      __hip_atomic_store(
          &hbuf[((size_t)(((((t + 1) & 1) * 2) + d) * 64 + seqbase + seq_i)) * 512 +
                (c0 + col_i)],
          pk, __ATOMIC_RELAXED, __HIP_MEMORY_SCOPE_AGENT);
    }
  };

  for (int t = 0; t < 128; ++t) {
    // phase 1: waves 0-2 GEMM fwd(t) ; waves 3-5 gather h_bwd(t) + stage x_bwd(t)
    if (wave < 3) do_gemm(0, wave);
    else if (t > 0) do_gather_stage(1, t, t & 1, (unsigned)t, tid - 192);
    __syncthreads();
    if (tid < 128) do_gates(0, t);
    // phase 2: waves 3-5 GEMM bwd(t) ; waves 0-2 gather h_fwd(t+1) + stage x_fwd(t+1)
    if (wave >= 3) do_gemm(1, wave - 3);
    else if (t < 127) do_gather_stage(0, t + 1, (t + 1) & 1, (unsigned)(t + 1), tid);
    __syncthreads();
    if (tid < 128) do_gates(1, t);
  }

  if (tid < 128) {   // seq1 + seq2 = mean + max over T
    y_seq[(size_t)(seqbase + seq_i) * 1024 + c0 + col_i] =
        msum[0] * (1.0f / 128.0f) + mx[0];
    y_seq[(size_t)(seqbase + seq_i) * 1024 + 512 + c0 + col_i] =
        msum[1] * (1.0f / 128.0f) + mx[1];
  }
}

// ---------------- launcher ----------------
extern "C" void kernel_launch(void* const* d_in, const int* in_sizes, int n_in,
                              void* d_out, int out_size, void* d_ws, size_t ws_size,
                              hipStream_t stream) {
  const float* x      = (const float*)d_in[0];
  const int*   eidx   = (const int*)d_in[1];
  const float* seq    = (const float*)d_in[2];
  const int*   batch  = (const int*)d_in[3];
  const float* wih_f  = (const float*)d_in[4];
  const float* whh_f  = (const float*)d_in[5];
  const float* bih_f  = (const float*)d_in[6];
  const float* bhh_f  = (const float*)d_in[7];
  const float* wih_b  = (const float*)d_in[8];
  const float* whh_b  = (const float*)d_in[9];
  const float* bih_b  = (const float*)d_in[10];
  const float* bhh_b  = (const float*)d_in[11];
  const float* mg_w0  = (const float*)d_in[12];
  const float* mg_b0  = (const float*)d_in[13];
  const float* mg_w1  = (const float*)d_in[14];
  const float* mg_b1  = (const float*)d_in[15];
  const float* mg_w2  = (const float*)d_in[16];
  const float* mg_b2  = (const float*)d_in[17];
  const float* ms_w0  = (const float*)d_in[18];
  const float* ms_b0  = (const float*)d_in[19];
  const float* ms_w1  = (const float*)d_in[20];
  const float* ms_b1  = (const float*)d_in[21];
  const float* ms_w2  = (const float*)d_in[22];
  const float* ms_b2  = (const float*)d_in[23];
  float* out = (float*)d_out;
  char* ws = (char*)d_ws;

  int*   deg     = (int*)(ws + OFF_DEG);
  int*   csrc    = (int*)(ws + OFF_CSRC);
  int*   cntb    = (int*)(ws + OFF_CNTB);
  unsigned* mhbar= (unsigned*)(ws + OFF_MHBAR);
  int*   flag    = (int*)(ws + OFF_FLAG64);
  int*   row_ptr = (int*)(ws + OFF_ROWPTR);
  int*   cursor  = (int*)(ws + OFF_CURSOR);
  float* dinv    = (float*)(ws + OFF_DINV);
  int*   colA    = (int*)(ws + OFF_COL);
  float* wgtA    = (float*)(ws + OFF_WGT);
  float* V0      = (float*)(ws + OFF_V0);
  float* V1      = (float*)(ws + OFF_V1);
  unsigned* hbuf = (unsigned*)(ws + OFF_HBUF);
  float* y_seq   = (float*)(ws + OFF_YSEQ);
  float* part    = (float*)(ws + OFF_PART);

  hipFuncSetAttribute((const void*)gru_kernel,
                      hipFuncAttributeMaxDynamicSharedMemorySize, GRU_LDS_BYTES);

  // ---- graph prep ----
  prep_kernel<<<(ZERO_INTS + 255) / 256 + 1, 256, 0, stream>>>((int*)ws, eidx, flag);
  hist_kernel<<<(NE + 255) / 256, 256, 0, stream>>>(eidx, batch, deg, csrc, cntb, flag);
  dinv_kernel<<<(NN + 255) / 256, 256, 0, stream>>>(deg, dinv);
  scan_kernel<<<1, 1024, 0, stream>>>(csrc, row_ptr, cursor);
  fill_kernel<<<(NE + 255) / 256, 256, 0, stream>>>(eidx, dinv, cursor, colA, wgtA, flag);
  v0init_kernel<<<(NN * 64 + 255) / 256, 256, 0, stream>>>(batch, V0, flag);

  // ---- APPNP: all 16 hops in one persistent kernel ----
  multihop_kernel<<<256, 1024, 0, stream>>>(V0, V1, row_ptr, colA, wgtA, dinv,
                                            batch, flag, mhbar);

  // ---- BiGRU (fused gi + recurrent + pooling) ----
  gru_kernel<<<256, 384, GRU_LDS_BYTES, stream>>>(
      seq, wih_f, whh_f, bih_f, bhh_f, wih_b, whh_b, bih_b, bhh_b, hbuf, y_seq);

  // ---- pooled partials: S^T x (result of 16 hops is in V0) ----
  spmm_kernel<<<(1536 * 64) / 256, 256, 0, stream>>>(V0, x, part);

  // ---- both readout MLPs + pooled reduce + final add ----
  heads_kernel<<<64, 256, 0, stream>>>(y_seq, part, cntb,
                                       ms_w0, ms_b0, ms_w1, ms_b1, ms_w2, ms_b2,
                                       mg_w0, mg_b0, mg_w1, mg_b1, mg_w2, mg_b2, out);
  (void)in_sizes; (void)n_in; (void)out_size; (void)ws_size;
}